// Round 6
// baseline (514.218 us; speedup 1.0000x reference)
//
#include <hip/hip_runtime.h>
#include <math.h>

// Problem constants: B=2,S=1024 -> T=2048 tokens; H=1024; I=2048; E=8; TOP_K=2
#define T_TOK 2048
#define H_DIM 1024
#define I_DIM 2048
#define NEXP  8

typedef _Float16 f16x8 __attribute__((ext_vector_type(8)));
typedef _Float16 f16x4 __attribute__((ext_vector_type(4)));
typedef float    f32x4 __attribute__((ext_vector_type(4)));

// ---------------------------------------------------------------------------
// async 16B global->LDS copy. LDS dest = WAVE-UNIFORM base + lane*16.
// ---------------------------------------------------------------------------
__device__ __forceinline__ void cp16(const void* g, void* l) {
  __builtin_amdgcn_global_load_lds(
      (const __attribute__((address_space(1))) void*)g,
      (__attribute__((address_space(3))) void*)l, 16, 0, 0);
}

#define WAITV(N) asm volatile("s_waitcnt vmcnt(" #N ")" ::: "memory")
#define SB0() __builtin_amdgcn_sched_barrier(0)
#define BAR() __builtin_amdgcn_s_barrier()

// ---------------------------------------------------------------------------
// fp32 -> f16 streaming convert (standalone; used for dwn when ws is small).
// ---------------------------------------------------------------------------
__global__ __launch_bounds__(256) void cvt_f16_kernel(
    const float* __restrict__ in, _Float16* __restrict__ hi, int n) {
  int i = (blockIdx.x * 256 + threadIdx.x) * 4;
  if (i >= n) return;
  float4 v = *(const float4*)(in + i);
  f16x4 hv = {(_Float16)v.x, (_Float16)v.y, (_Float16)v.z, (_Float16)v.w};
  *(f16x4*)(hi + i) = hv;
}

// ---------------------------------------------------------------------------
// PREP (fused): router + gram-zero + cvt x + cvt gup [+ cvt dwn if doDwn].
// ---------------------------------------------------------------------------
__global__ __launch_bounds__(256) void prep_kernel(
    const float* __restrict__ x, _Float16* __restrict__ xHi,
    const float* __restrict__ gup, _Float16* __restrict__ gup16,
    const float* __restrict__ dwn, _Float16* __restrict__ wd16,
    const float* __restrict__ gw,
    int* __restrict__ topIdx, float* __restrict__ topW,
    float* __restrict__ gram) {
  const int b = blockIdx.x;
  const int tid = threadIdx.x;

  if (b < 512) {
    if (b == 0 && tid < 36) gram[tid] = 0.f;
    const int wave = tid >> 6, lane = tid & 63;
    const int t = b * 4 + wave;
    float p[NEXP];
#pragma unroll
    for (int e = 0; e < NEXP; ++e) p[e] = 0.f;
    const float* xr = x + (size_t)t * H_DIM;
    for (int h = lane; h < H_DIM; h += 64) {
      float xv = xr[h];
#pragma unroll
      for (int e = 0; e < NEXP; ++e) p[e] += xv * gw[e * H_DIM + h];
    }
#pragma unroll
    for (int e = 0; e < NEXP; ++e) {
      float v = p[e];
      for (int off = 32; off > 0; off >>= 1) v += __shfl_down(v, off);
      p[e] = v;
    }
    if (lane == 0) {
      float mx = p[0];
#pragma unroll
      for (int e = 1; e < NEXP; ++e) mx = fmaxf(mx, p[e]);
      float ex[NEXP], s = 0.f;
#pragma unroll
      for (int e = 0; e < NEXP; ++e) { ex[e] = expf(p[e] - mx); s += ex[e]; }
#pragma unroll
      for (int e = 0; e < NEXP; ++e) ex[e] /= s;
      int i0 = 0; float v0 = ex[0];
#pragma unroll
      for (int e = 1; e < NEXP; ++e) if (ex[e] > v0) { v0 = ex[e]; i0 = e; }
      int i1 = -1; float v1 = -1.f;
#pragma unroll
      for (int e = 0; e < NEXP; ++e) if (e != i0 && ex[e] > v1) { v1 = ex[e]; i1 = e; }
      float sum = fmaxf(v0 + v1, 1e-12f);
      topIdx[2 * t] = i0;  topIdx[2 * t + 1] = i1;
      topW[2 * t] = v0 / sum;  topW[2 * t + 1] = v1 / sum;
    }
    return;
  }

  int rb = b - 512;
  const float* src;
  _Float16* dst;
  if (rb < 2048) {
    src = x;  dst = xHi;
  } else if (rb < 2048 + 32768) {
    rb -= 2048;  src = gup;  dst = gup16;
  } else {
    rb -= (2048 + 32768);  src = dwn;  dst = wd16;
  }
  const size_t i = (size_t)rb * 1024 + (size_t)tid * 4;
  float4 v = *(const float4*)(src + i);
  f16x4 hv = {(_Float16)v.x, (_Float16)v.y, (_Float16)v.z, (_Float16)v.w};
  *(f16x4*)(dst + i) = hv;
}

// ---------------------------------------------------------------------------
// Fused gate+up GEMM, counted-vmcnt 3-deep pipeline (T4).
// Shape: 128M x 256N-eff, 8 waves (2M x 4N), BK=64, 512 thr, 1 block/CU.
// B-tile (256 rows) is a GATHER: tile row r -> gup16 row
//   (r&63)>=32 ? U : G, col colB0 + (r>>6)*32 + ((r&63)&31).
// Wave wn covers tile rows [wn*64, wn*64+64): j=0,1 -> G cols, j=2,3 -> U of
// the SAME cols => silu(g)*u is lane-local: pair acc[i][j] with acc[i][j+2].
// LDS 144KB = 3 x {A 128x64 [0,16K) | B 256x64 [16K,48K)}.
// Swizzle: LDS chunk s of row r holds global k-chunk s ^ (r&7)
// (conflict-free, measured SQ_LDS_BANK_CONFLICT = 0).
// Pipeline per iter: vmcnt(12) [tile t landed; t+1,t+2 stay IN FLIGHT across
// the barrier] -> s_barrier -> compute(t) -> s_barrier -> stage t+3 into the
// freed buffer. Peeled tail: vmcnt(6), vmcnt(0). Wait-before-barrier makes
// the per-wave vmcnt a block-wide guarantee.
// ---------------------------------------------------------------------------
__global__ __launch_bounds__(512, 2) void gemm_gateup(
    const _Float16* __restrict__ xHi, const _Float16* __restrict__ gup16,
    _Float16* __restrict__ intHi) {
  __shared__ _Float16 lds[73728];  // 144 KB = 3 buffers x 24576 f16

  const int tid = threadIdx.x;
  const int wave = tid >> 6, lane = tid & 63;
  const int colB0 = blockIdx.x * 128;  // N tile within I
  const int rowA0 = blockIdx.y * 128;  // M tile
  const int e = blockIdx.z;

  // staging coords
  const int sr = lane >> 3;             // row within 8-row wave stripe
  const int sc = lane & 7;              // LDS chunk slot
  const int gcol = (sc ^ sr) * 8;       // swizzled global k-offset (f16 elems)

  // compute coords: 8 waves = 2M x 4N
  const int wm = wave >> 2;             // 0..1
  const int wn = wave & 3;              // 0..3
  const int fr = lane & 15;
  const int quad = lane >> 4;

  f32x4 acc[4][4];
#pragma unroll
  for (int i = 0; i < 4; ++i)
#pragma unroll
    for (int j = 0; j < 4; ++j) acc[i][j] = (f32x4){0.f, 0.f, 0.f, 0.f};

  // per-thread global staging bases
  const _Float16* aSrc = xHi + (size_t)(rowA0 + wave * 8 + sr) * H_DIM + gcol;
  // B slice c (c=0..3): tile rows c*64 + wave*8 + sr ->
  //   gup16 row = e*2I + (wave>>2)*I + colB0 + c*32 + (wave&3)*8 + sr
  const _Float16* bSrc = gup16 +
      ((size_t)e * 2 * I_DIM + (size_t)(wave >> 2) * I_DIM + colB0 +
       (wave & 3) * 8 + sr) * H_DIM + gcol;
  char* ldsB = (char*)lds;
  const unsigned wb = wave * 1024u;

  auto STAGE = [&](unsigned bufByte, int kt) {
    const int k0 = kt * 64;
#pragma unroll
    for (int c = 0; c < 2; ++c)
      cp16(aSrc + (size_t)c * 64 * H_DIM + k0, ldsB + bufByte + c * 8192u + wb);
#pragma unroll
    for (int c = 0; c < 4; ++c)
      cp16(bSrc + (size_t)c * 32 * H_DIM + k0,
           ldsB + bufByte + 16384u + c * 8192u + wb);
  };

  auto COMPUTE = [&](int bufElem) {
#pragma unroll
    for (int kk = 0; kk < 2; ++kk) {
      const int ksl = kk * 4 + quad;
      f16x8 ah[4];
#pragma unroll
      for (int i = 0; i < 4; ++i) {
        const int row = wm * 64 + i * 16 + fr;
        ah[i] = *(const f16x8*)&lds[bufElem + row * 64 + ((ksl ^ (fr & 7)) * 8)];
      }
#pragma unroll
      for (int j = 0; j < 4; ++j) {
        const int row = wn * 64 + j * 16 + fr;
        f16x8 bh = *(const f16x8*)&lds[bufElem + 8192 + row * 64 + ((ksl ^ (fr & 7)) * 8)];
#pragma unroll
        for (int i = 0; i < 4; ++i)
          acc[i][j] = __builtin_amdgcn_mfma_f32_16x16x32_f16(ah[i], bh, acc[i][j], 0, 0, 0);
      }
    }
  };

  const int NT = H_DIM / 64;  // 16
  // prologue: 3 tiles in flight (18 cp16/wave)
  STAGE(0u, 0);
  STAGE(49152u, 1);
  STAGE(98304u, 2);

  int cur = 0;
  for (int t = 0; t < NT - 2; ++t) {
    WAITV(12); SB0();
    BAR(); SB0();
    COMPUTE(cur * 24576);
    SB0(); BAR(); SB0();
    if (t + 3 < NT) STAGE((unsigned)cur * 49152u, t + 3);
    cur = (cur == 2) ? 0 : cur + 1;
  }
  WAITV(6); SB0();
  BAR(); SB0();
  COMPUTE(cur * 24576);
  cur = (cur == 2) ? 0 : cur + 1;
  WAITV(0); SB0();
  BAR(); SB0();
  COMPUTE(cur * 24576);

  // epilogue: C/D layout col=lane&15, row=quad*4+reg.
  // acc[i][jj] = gate, acc[i][jj+2] = up of the same output col.
  const int er = quad * 4;
  const int ec = lane & 15;
#pragma unroll
  for (int i = 0; i < 4; ++i)
#pragma unroll
    for (int jj = 0; jj < 2; ++jj) {
      const int row = rowA0 + wm * 64 + i * 16 + er;
      const int col = colB0 + wn * 32 + jj * 16 + ec;
#pragma unroll
      for (int r = 0; r < 4; ++r) {
        float g = acc[i][jj][r], u = acc[i][jj + 2][r];
        float val = g / (1.f + __expf(-g)) * u;
        intHi[((size_t)e * T_TOK + row + r) * I_DIM + col] = (_Float16)val;
      }
    }
}

// ---------------------------------------------------------------------------
// Down GEMM, same counted-vmcnt 3-deep pipeline. 128M x 256N, 8 waves, BK=64.
// eo[e][t][h] (f16) = inter @ wd16^T.  M=T(2048), N=H(1024), K=I(2048).
// GRID: x = M-tile(16), y = N-tile(4), z = expert(8). Same-A blocks (vary y)
// have ids differing by 16 == 0 mod 8 -> same XCD -> A-slab L2 reuse.
// LDS 144KB = 3 x {A 128x64 | B 256x64}; same swizzle (conflict-free).
// ---------------------------------------------------------------------------
__global__ __launch_bounds__(512, 2) void gemm_down(
    const _Float16* __restrict__ intHi, const _Float16* __restrict__ wd16,
    _Float16* __restrict__ eo) {
  __shared__ _Float16 lds[73728];  // 144 KB

  const int tid = threadIdx.x;
  const int wave = tid >> 6, lane = tid & 63;
  const int rowA0 = blockIdx.x * 128;
  const int colB0 = blockIdx.y * 256;
  const int e = blockIdx.z;

  const int sr = lane >> 3;
  const int sc = lane & 7;
  const int gcol = (sc ^ sr) * 8;

  const int wm = wave >> 2;
  const int wn = wave & 3;
  const int fr = lane & 15;
  const int quad = lane >> 4;

  f32x4 acc[4][4];
#pragma unroll
  for (int i = 0; i < 4; ++i)
#pragma unroll
    for (int j = 0; j < 4; ++j) acc[i][j] = (f32x4){0.f, 0.f, 0.f, 0.f};

  const _Float16* aSrc = intHi + (size_t)e * T_TOK * I_DIM +
                         (size_t)(rowA0 + wave * 8 + sr) * I_DIM + gcol;
  const _Float16* bSrc = wd16 +
      ((size_t)e * H_DIM + colB0 + wave * 8 + sr) * I_DIM + gcol;
  char* ldsB = (char*)lds;
  const unsigned wb = wave * 1024u;

  auto STAGE = [&](unsigned bufByte, int kt) {
    const int k0 = kt * 64;
#pragma unroll
    for (int c = 0; c < 2; ++c)
      cp16(aSrc + (size_t)c * 64 * I_DIM + k0, ldsB + bufByte + c * 8192u + wb);
#pragma unroll
    for (int c = 0; c < 4; ++c)
      cp16(bSrc + (size_t)c * 64 * I_DIM + k0,
           ldsB + bufByte + 16384u + c * 8192u + wb);
  };

  auto COMPUTE = [&](int bufElem) {
#pragma unroll
    for (int kk = 0; kk < 2; ++kk) {
      const int ksl = kk * 4 + quad;
      f16x8 ah[4];
#pragma unroll
      for (int i = 0; i < 4; ++i) {
        const int row = wm * 64 + i * 16 + fr;
        ah[i] = *(const f16x8*)&lds[bufElem + row * 64 + ((ksl ^ (fr & 7)) * 8)];
      }
#pragma unroll
      for (int j = 0; j < 4; ++j) {
        const int row = wn * 64 + j * 16 + fr;
        f16x8 bh = *(const f16x8*)&lds[bufElem + 8192 + row * 64 + ((ksl ^ (fr & 7)) * 8)];
#pragma unroll
        for (int i = 0; i < 4; ++i)
          acc[i][j] = __builtin_amdgcn_mfma_f32_16x16x32_f16(ah[i], bh, acc[i][j], 0, 0, 0);
      }
    }
  };

  const int NT = I_DIM / 64;  // 32
  STAGE(0u, 0);
  STAGE(49152u, 1);
  STAGE(98304u, 2);

  int cur = 0;
  for (int t = 0; t < NT - 2; ++t) {
    WAITV(12); SB0();
    BAR(); SB0();
    COMPUTE(cur * 24576);
    SB0(); BAR(); SB0();
    if (t + 3 < NT) STAGE((unsigned)cur * 49152u, t + 3);
    cur = (cur == 2) ? 0 : cur + 1;
  }
  WAITV(6); SB0();
  BAR(); SB0();
  COMPUTE(cur * 24576);
  cur = (cur == 2) ? 0 : cur + 1;
  WAITV(0); SB0();
  BAR(); SB0();
  COMPUTE(cur * 24576);

  const int er = quad * 4;
  const int ec = lane & 15;
#pragma unroll
  for (int i = 0; i < 4; ++i)
#pragma unroll
    for (int j = 0; j < 4; ++j) {
      const int row = rowA0 + wm * 64 + i * 16 + er;
      const int col = colB0 + wn * 64 + j * 16 + ec;
#pragma unroll
      for (int r = 0; r < 4; ++r)
        eo[((size_t)e * T_TOK + row + r) * H_DIM + col] = (_Float16)acc[i][j][r];
    }
}

// ---------------------------------------------------------------------------
// Gram: gram36[p] = sum_j eo[a][j]*eo[b][j] for pairs a<=b. f16x8 loads.
// ---------------------------------------------------------------------------
__global__ __launch_bounds__(256) void gram_kernel(
    const _Float16* __restrict__ eo, float* __restrict__ gram) {
  float s[36];
#pragma unroll
  for (int p = 0; p < 36; ++p) s[p] = 0.f;
  const size_t total = (size_t)T_TOK * H_DIM;
  const size_t stride = (size_t)gridDim.x * 256 * 8;
  for (size_t j = ((size_t)blockIdx.x * 256 + threadIdx.x) * 8; j < total; j += stride) {
    f16x8 ve[NEXP];
#pragma unroll
    for (int e = 0; e < NEXP; ++e) ve[e] = *(const f16x8*)&eo[(size_t)e * total + j];
#pragma unroll
    for (int k = 0; k < 8; ++k) {
      float v[NEXP];
#pragma unroll
      for (int e = 0; e < NEXP; ++e) v[e] = (float)ve[e][k];
      int p = 0;
#pragma unroll
      for (int a = 0; a < NEXP; ++a)
#pragma unroll
        for (int b = a; b < NEXP; ++b) { s[p] += v[a] * v[b]; ++p; }
    }
  }
#pragma unroll
  for (int p = 0; p < 36; ++p) {
    float v = s[p];
    for (int off = 32; off > 0; off >>= 1) v += __shfl_down(v, off);
    s[p] = v;
  }
  __shared__ float red[4][36];
  const int wave = threadIdx.x >> 6, lane = threadIdx.x & 63;
  if (lane == 0)
#pragma unroll
    for (int p = 0; p < 36; ++p) red[wave][p] = s[p];
  __syncthreads();
  if (threadIdx.x < 36) {
    float v = red[0][threadIdx.x] + red[1][threadIdx.x] + red[2][threadIdx.x] + red[3][threadIdx.x];
    atomicAdd(&gram[threadIdx.x], v);
  }
}

// ---------------------------------------------------------------------------
// Final (+fused sim): blocks [0,T_TOK) do out[t] = w0*eo[i0][t]+w1*eo[i1][t];
// block T_TOK (threads 0..63) computes the 8x8 similarity from gram36.
// ---------------------------------------------------------------------------
__global__ __launch_bounds__(256) void final_kernel(
    const _Float16* __restrict__ eo, const int* __restrict__ topIdx,
    const float* __restrict__ topW, const float* __restrict__ gram,
    float* __restrict__ out) {
  const int t = blockIdx.x;
  if (t == T_TOK) {
    if (threadIdx.x < 64) {
      const int q = threadIdx.x;
      const int e1 = q >> 3, e2 = q & 7;
      int a = e1 < e2 ? e1 : e2;
      int b = e1 < e2 ? e2 : e1;
      const float g = gram[a * 8 - a * (a - 1) / 2 + (b - a)];
      const float sq1 = gram[e1 * 8 - e1 * (e1 - 1) / 2];
      const float sq2 = gram[e2 * 8 - e2 * (e2 - 1) / 2];
      float d2 = fmaxf(sq1 + sq2 - 2.f * g, 0.f);
      float dist = (e1 == e2) ? 0.f : sqrtf(d2);
      float dmax = dist;
      for (int off = 32; off > 0; off >>= 1) dmax = fmaxf(dmax, __shfl_xor(dmax, off));
      float sim = 1.f - dist / fmaxf(dmax, 1e-12f);
      if (e1 == e2) sim = 1.f;
      out[(size_t)T_TOK * H_DIM + q] = sim;
    }
    return;
  }
  const int c = threadIdx.x * 4;
  const int i0 = topIdx[2 * t], i1 = topIdx[2 * t + 1];
  const float w0 = topW[2 * t], w1 = topW[2 * t + 1];
  const size_t per = (size_t)T_TOK * H_DIM;
  f16x4 a = *(const f16x4*)&eo[(size_t)i0 * per + (size_t)t * H_DIM + c];
  f16x4 b = *(const f16x4*)&eo[(size_t)i1 * per + (size_t)t * H_DIM + c];
  float4 r;
  r.x = w0 * (float)a[0] + w1 * (float)b[0];
  r.y = w0 * (float)a[1] + w1 * (float)b[1];
  r.z = w0 * (float)a[2] + w1 * (float)b[2];
  r.w = w0 * (float)a[3] + w1 * (float)b[3];
  *(float4*)&out[(size_t)t * H_DIM + c] = r;
}

// ---------------------------------------------------------------------------
// Workspace layout, liveness-aliased base plan (needs 132 MiB + 48 KiB):
//  xHi @0 (4 MiB) | intHi @4 MiB (64 MiB)
//  gup16 @68 MiB (64 MiB, dead after gemm_gateup)
//  wd16 @68 MiB (32 MiB, born after gateup) -- UNLESS ws >= 169 MiB, then
//    wd16 @136 MiB and its cvt folds into prep (one fewer launch).
//  eo @100 MiB (32 MiB) | topIdx @132 MiB | topW +16K | gram +32K
// ---------------------------------------------------------------------------
extern "C" void kernel_launch(void* const* d_in, const int* in_sizes, int n_in,
                              void* d_out, int out_size, void* d_ws, size_t ws_size,
                              hipStream_t stream) {
  (void)in_sizes; (void)n_in; (void)out_size;
  const float* x   = (const float*)d_in[0];  // (2,1024,1024)
  const float* gw  = (const float*)d_in[1];  // (8,1024)
  const float* gup = (const float*)d_in[2];  // (8,4096,1024)
  const float* dwn = (const float*)d_in[3];  // (8,1024,2048)
  float* out = (float*)d_out;                // final (2M) ++ sim (64)

  char* ws = (char*)d_ws;
  const size_t MB = 1u << 20;
  _Float16* xHi    = (_Float16*)(ws + 0 * MB);
  _Float16* intHi  = (_Float16*)(ws + 4 * MB);
  _Float16* gup16  = (_Float16*)(ws + 68 * MB);
  _Float16* eo     = (_Float16*)(ws + 100 * MB);
  int*      topIdx = (int*)(ws + 132 * MB);
  float*    topW   = (float*)(ws + 132 * MB + 16384);
  float*    gram   = (float*)(ws + 132 * MB + 32768);

  const int doDwn = ws_size >= (size_t)169 * MB;
  _Float16* wd16 = doDwn ? (_Float16*)(ws + 136 * MB)
                         : (_Float16*)(ws + 68 * MB);  // aliases gup16

  // fused prep: router + gram-zero + cvt x + cvt gup [+ cvt dwn]
  const int prepBlocks = 512 + 2048 + 32768 + (doDwn ? 16384 : 0);
  prep_kernel<<<prepBlocks, 256, 0, stream>>>(
      x, xHi, gup, gup16, dwn, wd16, gw, topIdx, topW, gram);

  // gate+up fused: grid x=N(16), y=M(16), z=E(8); same-B blocks co-XCD
  gemm_gateup<<<dim3(I_DIM / 128, T_TOK / 128, NEXP), 512, 0, stream>>>(
      xHi, gup16, intHi);

  // dwn -> f16 AFTER gateup only when wd16 must alias gup16's region
  if (!doDwn)
    cvt_f16_kernel<<<16384, 256, 0, stream>>>(dwn, wd16, NEXP * H_DIM * I_DIM);

  // down: grid x=M(16), y=N(4), z=E(8); same-A blocks co-XCD
  gemm_down<<<dim3(T_TOK / 128, H_DIM / 256, NEXP), 512, 0, stream>>>(
      intHi, wd16, eo);

  gram_kernel<<<1024, 256, 0, stream>>>(eo, gram);
  final_kernel<<<T_TOK + 1, 256, 0, stream>>>(eo, topIdx, topW, gram, out);
}